// Round 13
// baseline (82.405 us; speedup 1.0000x reference)
//
#include <hip/hip_runtime.h>
#include <hip/hip_bf16.h>

typedef __attribute__((ext_vector_type(8))) short bf16x8;
typedef __attribute__((ext_vector_type(4))) float f32x4;

#define NB 8192
#define NS 8

__device__ __forceinline__ unsigned short f2bf(float f) {
  union { float f; unsigned int u; } v; v.f = f;
  unsigned int r = v.u + 0x7FFFu + ((v.u >> 16) & 1u);
  return (unsigned short)(r >> 16);
}

// Single fused kernel. Block = one group, 512 threads (8 waves), 2 blocks/CU.
// Prologue (pre-barrier, work-split): waves 0-3 hW tile via MFMA (h,W1b
// converted from global f32); waves 4-6 wc dot-products (16-way ILP) into LDS;
// all waves convert their pass-0 W2 B-fragments from f32.
// Phase 1: A (tile=j) into LDS in fragment order, bias folded here.
// Phase 2: R12's register-pool j-loop (2 passes of 4 ntiles, acc dbuf);
// pass-1 B-fragments loaded from W2 between passes. Normal stores.
__global__ __launch_bounds__(512, 4) void pool_kernel(
    const float* __restrict__ in_xy, const float* __restrict__ h_states,
    const float* __restrict__ W_emb, const float* __restrict__ b_emb,
    const float* __restrict__ W1, const float* __restrict__ b1,
    const float* __restrict__ W2, const float* __restrict__ b2,
    float* __restrict__ out) {
  __shared__ bf16x8 Afrag[2048];  // 32 KB, fragment-ordered A (256x64 bf16), tile=j
  __shared__ float hWs[16][72];   // hW tile, NO bias (pad 72)
  __shared__ float wcs[192];      // wc0[64], wc1[64], cbe[64]
  __shared__ float exy[32];       // x[0:16], y[16:32]
  const int g = blockIdx.x;
  const int t = threadIdx.x;
  const int lane = t & 63;
  const int wv = t >> 6;  // 0..7

  if (t < 32) {
    int p = t & 15;
    exy[t] = in_xy[((NS - 1) * NB + g * 16 + p) * 2 + (t >> 4)];
  }

  // Prologue A: waves 0-3 -> hW[j][col] = h[g*16+j] @ W1b (no bias), ntile wv.
  if (wv < 4) {
    const int row = g * 16 + (lane & 15);
    const int e0 = (lane >> 4) * 8;
    const float* hp = h_states + row * 64 + e0;
    const float* wp = W1 + (64 + e0) * 64 + wv * 16 + (lane & 15);
    bf16x8 ha0, ha1, bf0, bf1;
#pragma unroll
    for (int e = 0; e < 8; ++e) {
      ha0[e] = (short)f2bf(hp[e]);
      ha1[e] = (short)f2bf(hp[e + 32]);
      bf0[e] = (short)f2bf(wp[e * 64]);
      bf1[e] = (short)f2bf(wp[(e + 32) * 64]);
    }
    f32x4 z = {0.f, 0.f, 0.f, 0.f};
    f32x4 acc = __builtin_amdgcn_mfma_f32_16x16x32_bf16(ha0, bf0, z, 0, 0, 0);
    acc = __builtin_amdgcn_mfma_f32_16x16x32_bf16(ha1, bf1, acc, 0, 0, 0);
    int col = wv * 16 + (lane & 15);
#pragma unroll
    for (int r = 0; r < 4; ++r)
      hWs[(lane >> 4) * 4 + r][col] = acc[r];
  } else if (t < 448) {
    // Prologue B: waves 4-6 -> wc (192 dots of length 64), 16-way ILP.
    int t2 = t - 256;
    int c = t2 >> 6, k = t2 & 63;
    const float* src = (c == 0) ? W_emb : (c == 1) ? (W_emb + 64) : b_emb;
    float s[16];
#pragma unroll
    for (int q = 0; q < 16; ++q) s[q] = 0.f;
#pragma unroll
    for (int e = 0; e < 64; e += 16)
#pragma unroll
      for (int q = 0; q < 16; ++q)
        s[q] = fmaf(src[e + q], W1[(e + q) * 64 + k], s[q]);
#pragma unroll
    for (int off = 8; off > 0; off >>= 1)
#pragma unroll
      for (int q = 0; q < off; ++q) s[q] += s[q + off];
    wcs[t2] = s[0];
  }

  // Per-thread constants (global, L2-hot; no LDS dep)
  float b2v[8];
#pragma unroll
  for (int u = 0; u < 8; ++u)
    b2v[u] = b2[wv * 128 + u * 16 + (lane & 15)];
  const int i = t & 15;
  const int k0 = ((t >> 6) & 1) * 32 + ((t >> 4) & 3) * 8;
  float b1v[8];
#pragma unroll
  for (int e = 0; e < 8; ++e) b1v[e] = b1[k0 + e];

  // Pass-0 B-fragments: convert from W2 f32 (per granule: 8 dword loads,
  // each 4x64B coalesced). Issued after wc/hW so their chains aren't delayed.
  const float* w2l = W2 + ((lane >> 4) * 8) * 1024 + (lane & 15);
  bf16x8 bfr[4][2];
#pragma unroll
  for (int u = 0; u < 4; ++u) {
#pragma unroll
    for (int ks = 0; ks < 2; ++ks) {
      const float* p = w2l + ks * 32 * 1024 + (wv * 8 + u) * 16;
      float tmp[8];
#pragma unroll
      for (int e = 0; e < 8; ++e) tmp[e] = p[e * 1024];
      bf16x8 pk;
#pragma unroll
      for (int e = 0; e < 8; ++e) pk[e] = (short)f2bf(tmp[e]);
      bfr[u][ks] = pk;
    }
  }
  __syncthreads();

  // Phase 1: A build. Granule G = t + 512c -> j = (t>>7)+4c.
  // A_j[i,k] = relu(rel_x*wc0[k] + rel_y*wc1[k] + hW[j][k] + b1[k] + cbe[k])
  {
    float w0[8], w1[8], bias8[8];
#pragma unroll
    for (int e = 0; e < 8; ++e) {
      w0[e] = wcs[k0 + e];
      w1[e] = wcs[64 + k0 + e];
      bias8[e] = b1v[e] + wcs[128 + k0 + e];
    }
    float exi = exy[i], eyi = exy[16 + i];
#pragma unroll
    for (int c = 0; c < 4; ++c) {
      int j = (t >> 7) + 4 * c;
      float rx = exy[j] - exi;
      float ry = exy[16 + j] - eyi;
      const f32x4* hp2 = (const f32x4*)&hWs[j][k0];
      f32x4 h0 = hp2[0], h1 = hp2[1];
      float hv[8] = {h0[0], h0[1], h0[2], h0[3], h1[0], h1[1], h1[2], h1[3]};
      bf16x8 pk;
#pragma unroll
      for (int e = 0; e < 8; ++e) {
        float v = fmaf(rx, w0[e], fmaf(ry, w1[e], hv[e] + bias8[e]));
        v = fmaxf(v, 0.f);
        pk[e] = (short)f2bf(v);
      }
      Afrag[t + 512 * c] = pk;
    }
  }
  __syncthreads();

  // Phase 2: GEMM + register pooling, 2 passes of 4 ntiles, acc double-buffer.
  const int rowbase = (g * 16 + (lane >> 4) * 4) * 1024 + wv * 128 + (lane & 15);
  const bf16x8* ap = Afrag + lane;
  const f32x4 NEGINF = {-3.4e38f, -3.4e38f, -3.4e38f, -3.4e38f};
#pragma unroll
  for (int pass = 0; pass < 2; ++pass) {
    f32x4 pool[4], accB[4];
#pragma unroll
    for (int u = 0; u < 4; ++u) { pool[u] = NEGINF; accB[u] = NEGINF; }

    bf16x8 a0 = ap[0];
    bf16x8 a1 = ap[64];
#pragma unroll
    for (int jj = 0; jj < 16; jj += 2) {
      // even iter -> accA; pool-fmax consumes accB (iter jj-1; -inf at jj=0)
      f32x4 accA[4];
      __builtin_amdgcn_s_setprio(1);
#pragma unroll
      for (int u = 0; u < 4; ++u) {
        f32x4 z = {0.f, 0.f, 0.f, 0.f};
        accA[u] = __builtin_amdgcn_mfma_f32_16x16x32_bf16(a0, bfr[u][0], z, 0, 0, 0);
      }
#pragma unroll
      for (int u = 0; u < 4; ++u)
        accA[u] = __builtin_amdgcn_mfma_f32_16x16x32_bf16(a1, bfr[u][1], accA[u], 0, 0, 0);
      __builtin_amdgcn_s_setprio(0);
      bf16x8 c0 = ap[(jj + 1) * 128];
      bf16x8 c1 = ap[(jj + 1) * 128 + 64];
#pragma unroll
      for (int u = 0; u < 4; ++u)
#pragma unroll
        for (int r = 0; r < 4; ++r) pool[u][r] = fmaxf(pool[u][r], accB[u][r]);

      // odd iter -> accB; pool-fmax consumes accA
      __builtin_amdgcn_s_setprio(1);
#pragma unroll
      for (int u = 0; u < 4; ++u) {
        f32x4 z = {0.f, 0.f, 0.f, 0.f};
        accB[u] = __builtin_amdgcn_mfma_f32_16x16x32_bf16(c0, bfr[u][0], z, 0, 0, 0);
      }
#pragma unroll
      for (int u = 0; u < 4; ++u)
        accB[u] = __builtin_amdgcn_mfma_f32_16x16x32_bf16(c1, bfr[u][1], accB[u], 0, 0, 0);
      __builtin_amdgcn_s_setprio(0);
      int jn = (jj + 2) & 15;  // wrap harmless
      a0 = ap[jn * 128];
      a1 = ap[jn * 128 + 64];
#pragma unroll
      for (int u = 0; u < 4; ++u)
#pragma unroll
        for (int r = 0; r < 4; ++r) pool[u][r] = fmaxf(pool[u][r], accA[u][r]);
    }
    // tail: accB holds j=15
#pragma unroll
    for (int u = 0; u < 4; ++u)
#pragma unroll
      for (int r = 0; r < 4; ++r) pool[u][r] = fmaxf(pool[u][r], accB[u][r]);

    // load pass-1 B-fragments from W2 (latency overlaps epilogue stores)
    if (pass == 0) {
#pragma unroll
      for (int u = 0; u < 4; ++u) {
#pragma unroll
        for (int ks = 0; ks < 2; ++ks) {
          const float* p = w2l + ks * 32 * 1024 + (wv * 8 + 4 + u) * 16;
          float tmp[8];
#pragma unroll
          for (int e = 0; e < 8; ++e) tmp[e] = p[e * 1024];
          bf16x8 pk;
#pragma unroll
          for (int e = 0; e < 8; ++e) pk[e] = (short)f2bf(tmp[e]);
          bfr[u][ks] = pk;
        }
      }
    }

#pragma unroll
    for (int u = 0; u < 4; ++u) {
      float bb = b2v[pass * 4 + u];
#pragma unroll
      for (int r = 0; r < 4; ++r)
        out[rowbase + r * 1024 + (pass * 4 + u) * 16] = fmaxf(pool[u][r] + bb, 0.f);
    }
  }
}

extern "C" void kernel_launch(void* const* d_in, const int* in_sizes, int n_in,
                              void* d_out, int out_size, void* d_ws, size_t ws_size,
                              hipStream_t stream) {
  const float* in_xy = (const float*)d_in[0];
  const float* h_states = (const float*)d_in[2];
  const float* W_emb = (const float*)d_in[4];
  const float* b_emb = (const float*)d_in[5];
  const float* W1 = (const float*)d_in[6];
  const float* b1 = (const float*)d_in[7];
  const float* W2 = (const float*)d_in[8];
  const float* b2 = (const float*)d_in[9];
  float* out = (float*)d_out;

  pool_kernel<<<512, 512, 0, stream>>>(in_xy, h_states, W_emb, b_emb, W1, b1,
                                       W2, b2, out);
}

// Round 14
// 70.456 us; speedup vs baseline: 1.1696x; 1.1696x over previous
//
#include <hip/hip_runtime.h>
#include <hip/hip_bf16.h>

typedef __attribute__((ext_vector_type(8))) short bf16x8;
typedef __attribute__((ext_vector_type(4))) float f32x4;

#define NB 8192
#define NS 8

__device__ __forceinline__ unsigned short f2bf(float f) {
  union { float f; unsigned int u; } v; v.f = f;
  unsigned int r = v.u + 0x7FFFu + ((v.u >> 16) & 1u);
  return (unsigned short)(r >> 16);
}

// prep: W2 -> bf16 B-fragments (w2f); Wc = [W_emb;b_emb]@W1a (wc);
//       W1b (rows 64..127) -> bf16 B-fragments (w1bf)
__global__ __launch_bounds__(256) void prep_kernel(
    const float* __restrict__ W2, const float* __restrict__ W_emb,
    const float* __restrict__ b_emb, const float* __restrict__ W1,
    unsigned short* __restrict__ w2f, float* __restrict__ wc,
    unsigned short* __restrict__ w1bf) {
  int tid = blockIdx.x * 256 + threadIdx.x;
  if (tid < 8192) {
    int lane = tid & 63;
    int ks = (tid >> 6) & 1;
    int nt = tid >> 7;
    int col = nt * 16 + (lane & 15);
    int k0 = ks * 32 + (lane >> 4) * 8;
    bf16x8 pk;
#pragma unroll
    for (int e = 0; e < 8; ++e)
      pk[e] = (short)f2bf(W2[(k0 + e) * 1024 + col]);
    *(bf16x8*)(w2f + tid * 8) = pk;
  } else if (tid < 8192 + 192) {
    int t2 = tid - 8192;
    int c = t2 >> 6, k = t2 & 63;
    float s = 0.f;
    for (int e = 0; e < 64; ++e) {
      float src = (c < 2) ? W_emb[c * 64 + e] : b_emb[e];
      s += src * W1[e * 64 + k];
    }
    wc[t2] = s;  // wc0[k], wc1[k], cbe[k]
  } else if (tid < 8192 + 192 + 512) {
    int q = tid - 8384;
    int lane = q & 63;
    int fr = q >> 6;          // nt*2 + ks
    int nt = fr >> 1, ks = fr & 1;
    int col = nt * 16 + (lane & 15);
    int e0 = ks * 32 + (lane >> 4) * 8;
    bf16x8 pk;
#pragma unroll
    for (int e = 0; e < 8; ++e)
      pk[e] = (short)f2bf(W1[(64 + e0 + e) * 64 + col]);
    *(bf16x8*)(w1bf + q * 8) = pk;
  }
}

// Phase 2 worker: 2 passes of 4 ntiles, acc double-buffer, register max-pool.
// J0 (compile-time) rotates the j iteration order so co-resident waves'
// MFMA/VALU bursts decorrelate; max is commutative so result is identical.
template <int J0>
__device__ __forceinline__ void phase2(
    const bf16x8* ap, const unsigned short* __restrict__ w2f, int wv, int lane,
    int rowbase, const float* b2v, float* __restrict__ out, bf16x8 (&bfr)[4][2]) {
  const f32x4 NEGINF = {-3.4e38f, -3.4e38f, -3.4e38f, -3.4e38f};
#pragma unroll
  for (int pass = 0; pass < 2; ++pass) {
    if (pass == 1) {
#pragma unroll
      for (int u = 0; u < 4; ++u) {
        int nt = wv * 8 + 4 + u;
        bfr[u][0] = *(const bf16x8*)(w2f + ((nt * 2 + 0) * 64 + lane) * 8);
        bfr[u][1] = *(const bf16x8*)(w2f + ((nt * 2 + 1) * 64 + lane) * 8);
      }
    }
    f32x4 pool[4], accB[4];
#pragma unroll
    for (int u = 0; u < 4; ++u) { pool[u] = NEGINF; accB[u] = NEGINF; }

    bf16x8 a0 = ap[((J0) & 15) * 128];
    bf16x8 a1 = ap[((J0) & 15) * 128 + 64];
#pragma unroll
    for (int jj = 0; jj < 16; jj += 2) {
      const int j1 = (jj + 1 + J0) & 15;
      const int j2 = (jj + 2 + J0) & 15;
      // even iter -> accA; pool-fmax consumes accB (prev iter; -inf at jj=0)
      f32x4 accA[4];
#pragma unroll
      for (int u = 0; u < 4; ++u) {
        f32x4 z = {0.f, 0.f, 0.f, 0.f};
        accA[u] = __builtin_amdgcn_mfma_f32_16x16x32_bf16(a0, bfr[u][0], z, 0, 0, 0);
      }
#pragma unroll
      for (int u = 0; u < 4; ++u)
        accA[u] = __builtin_amdgcn_mfma_f32_16x16x32_bf16(a1, bfr[u][1], accA[u], 0, 0, 0);
      bf16x8 c0 = ap[j1 * 128];
      bf16x8 c1 = ap[j1 * 128 + 64];
#pragma unroll
      for (int u = 0; u < 4; ++u)
#pragma unroll
        for (int r = 0; r < 4; ++r) pool[u][r] = fmaxf(pool[u][r], accB[u][r]);

      // odd iter -> accB; pool-fmax consumes accA
#pragma unroll
      for (int u = 0; u < 4; ++u) {
        f32x4 z = {0.f, 0.f, 0.f, 0.f};
        accB[u] = __builtin_amdgcn_mfma_f32_16x16x32_bf16(c0, bfr[u][0], z, 0, 0, 0);
      }
#pragma unroll
      for (int u = 0; u < 4; ++u)
        accB[u] = __builtin_amdgcn_mfma_f32_16x16x32_bf16(c1, bfr[u][1], accB[u], 0, 0, 0);
      a0 = ap[j2 * 128];
      a1 = ap[j2 * 128 + 64];
#pragma unroll
      for (int u = 0; u < 4; ++u)
#pragma unroll
        for (int r = 0; r < 4; ++r) pool[u][r] = fmaxf(pool[u][r], accA[u][r]);
    }
    // tail: accB holds the last j
#pragma unroll
    for (int u = 0; u < 4; ++u)
#pragma unroll
      for (int r = 0; r < 4; ++r) pool[u][r] = fmaxf(pool[u][r], accB[u][r]);

#pragma unroll
    for (int u = 0; u < 4; ++u) {
      float bb = b2v[pass * 4 + u];
#pragma unroll
      for (int r = 0; r < 4; ++r)
        out[rowbase + r * 1024 + (pass * 4 + u) * 16] = fmaxf(pool[u][r] + bb, 0.f);
    }
  }
}

// pool: block = one group, 512 threads (8 waves), launch_bounds(512,4) ->
// 2 blocks/CU, 16 waves/CU. Phase 0: hW tile via MFMA (waves 0-3);
// Phase 1: A (tile=j) into LDS in fragment order; pass-0 B-frags issued
// before the barrier. Phase 2: register-pool j-loop, odd waves rotated by 8.
__global__ __launch_bounds__(512, 4) void pool_kernel(
    const float* __restrict__ in_xy, const float* __restrict__ h_states,
    const float* __restrict__ b1, const float* __restrict__ b2,
    const unsigned short* __restrict__ w2f, const float* __restrict__ wc,
    const unsigned short* __restrict__ w1bf, float* __restrict__ out) {
  __shared__ bf16x8 Afrag[2048];  // 32 KB, fragment-ordered A (256x64 bf16), tile=j
  __shared__ float hWs[16][72];   // hW tile (pad 72 -> 16B-aligned rows)
  __shared__ float exy[32];       // x[0:16], y[16:32]
  const int g = blockIdx.x;
  const int t = threadIdx.x;
  const int lane = t & 63;
  const int wv = t >> 6;  // 0..7

  if (t < 32) {
    int p = t & 15;
    exy[t] = in_xy[((NS - 1) * NB + g * 16 + p) * 2 + (t >> 4)];
  }

  // Phase 0: hW[j][k] = b1[k] + cbe[k] + h[g*16+j] @ W1b. Waves 0-3 -> ntile wv.
  if (wv < 4) {
    const int row = g * 16 + (lane & 15);
    const int e0 = (lane >> 4) * 8;
    const float* hp = h_states + row * 64 + e0;
    bf16x8 ha0, ha1;
#pragma unroll
    for (int e = 0; e < 8; ++e) {
      ha0[e] = (short)f2bf(hp[e]);
      ha1[e] = (short)f2bf(hp[e + 32]);
    }
    bf16x8 bf0 = *(const bf16x8*)(w1bf + ((wv * 2 + 0) * 64 + lane) * 8);
    bf16x8 bf1 = *(const bf16x8*)(w1bf + ((wv * 2 + 1) * 64 + lane) * 8);
    f32x4 z = {0.f, 0.f, 0.f, 0.f};
    f32x4 acc = __builtin_amdgcn_mfma_f32_16x16x32_bf16(ha0, bf0, z, 0, 0, 0);
    acc = __builtin_amdgcn_mfma_f32_16x16x32_bf16(ha1, bf1, acc, 0, 0, 0);
    int col = wv * 16 + (lane & 15);
    float bb = b1[col] + wc[128 + col];
#pragma unroll
    for (int r = 0; r < 4; ++r)
      hWs[(lane >> 4) * 4 + r][col] = acc[r] + bb;
  }

  // epilogue bias + per-thread k-slice constants (global, L2-hot; no LDS dep)
  float b2v[8];
#pragma unroll
  for (int u = 0; u < 8; ++u)
    b2v[u] = b2[wv * 128 + u * 16 + (lane & 15)];
  const int i = t & 15;
  const int k0 = ((t >> 6) & 1) * 32 + ((t >> 4) & 3) * 8;
  float w0[8], w1[8];
#pragma unroll
  for (int e = 0; e < 8; ++e) {
    w0[e] = wc[k0 + e];
    w1[e] = wc[64 + k0 + e];
  }
  __syncthreads();

  // Phase 1: A build. Granule G = t + 512c -> lane=G&63, ks=(G>>6)&1,
  // j = (t>>7) + 4c. A_j[i,k] = relu(rel(i,j)x*wc0 + rel(i,j)y*wc1 + hW[j][k])
  {
    float exi = exy[i], eyi = exy[16 + i];
#pragma unroll
    for (int c = 0; c < 4; ++c) {
      int j = (t >> 7) + 4 * c;
      float rx = exy[j] - exi;
      float ry = exy[16 + j] - eyi;
      const f32x4* hp2 = (const f32x4*)&hWs[j][k0];
      f32x4 h0 = hp2[0], h1 = hp2[1];
      float hv[8] = {h0[0], h0[1], h0[2], h0[3], h1[0], h1[1], h1[2], h1[3]};
      bf16x8 pk;
#pragma unroll
      for (int e = 0; e < 8; ++e) {
        float v = fmaf(rx, w0[e], fmaf(ry, w1[e], hv[e]));
        v = fmaxf(v, 0.f);
        pk[e] = (short)f2bf(v);
      }
      Afrag[t + 512 * c] = pk;
    }
  }

  // Pass-0 B-fragments issued BEFORE the barrier: global-load latency overlaps
  // the barrier + other waves' A-build tail.
  bf16x8 bfr[4][2];
#pragma unroll
  for (int u = 0; u < 4; ++u) {
    int nt = wv * 8 + u;
    bfr[u][0] = *(const bf16x8*)(w2f + ((nt * 2 + 0) * 64 + lane) * 8);
    bfr[u][1] = *(const bf16x8*)(w2f + ((nt * 2 + 1) * 64 + lane) * 8);
  }
  __syncthreads();

  // Phase 2: odd waves iterate j rotated by 8 (identical result; decorrelates
  // matrix-pipe vs VALU bursts across co-resident waves).
  const int rowbase = (g * 16 + (lane >> 4) * 4) * 1024 + wv * 128 + (lane & 15);
  const bf16x8* ap = Afrag + lane;
  if (wv & 1)
    phase2<8>(ap, w2f, wv, lane, rowbase, b2v, out, bfr);
  else
    phase2<0>(ap, w2f, wv, lane, rowbase, b2v, out, bfr);
}

extern "C" void kernel_launch(void* const* d_in, const int* in_sizes, int n_in,
                              void* d_out, int out_size, void* d_ws, size_t ws_size,
                              hipStream_t stream) {
  const float* in_xy = (const float*)d_in[0];
  const float* h_states = (const float*)d_in[2];
  const float* W_emb = (const float*)d_in[4];
  const float* b_emb = (const float*)d_in[5];
  const float* W1 = (const float*)d_in[6];
  const float* b1 = (const float*)d_in[7];
  const float* W2 = (const float*)d_in[8];
  const float* b2 = (const float*)d_in[9];
  float* out = (float*)d_out;

  unsigned short* w2f = (unsigned short*)d_ws;                     // 128 KB @ 0
  float* wc = (float*)((char*)d_ws + 131072);                      // 768 B
  unsigned short* w1bf = (unsigned short*)((char*)d_ws + 132096);  // 8 KB

  prep_kernel<<<35, 256, 0, stream>>>(W2, W_emb, b_emb, W1, w2f, wc, w1bf);
  pool_kernel<<<512, 512, 0, stream>>>(in_xy, h_states, b1, b2, w2f, wc, w1bf, out);
}

// Round 15
// 26.416 us; speedup vs baseline: 3.1194x; 2.6671x over previous
//
#include <hip/hip_runtime.h>
#include <hip/hip_bf16.h>

typedef __attribute__((ext_vector_type(8))) short bf16x8;
typedef __attribute__((ext_vector_type(4))) float f32x4;

#define NB 8192
#define NS 8

__device__ __forceinline__ unsigned short f2bf(float f) {
  union { float f; unsigned int u; } v; v.f = f;
  unsigned int r = v.u + 0x7FFFu + ((v.u >> 16) & 1u);
  return (unsigned short)(r >> 16);
}

// prep: W2 -> bf16 B-fragments (w2f); Wc = [W_emb;b_emb]@W1a (wc);
//       W1b (rows 64..127) -> bf16 B-fragments (w1bf)
__global__ __launch_bounds__(256) void prep_kernel(
    const float* __restrict__ W2, const float* __restrict__ W_emb,
    const float* __restrict__ b_emb, const float* __restrict__ W1,
    unsigned short* __restrict__ w2f, float* __restrict__ wc,
    unsigned short* __restrict__ w1bf) {
  int tid = blockIdx.x * 256 + threadIdx.x;
  if (tid < 8192) {
    int lane = tid & 63;
    int ks = (tid >> 6) & 1;
    int nt = tid >> 7;
    int col = nt * 16 + (lane & 15);
    int k0 = ks * 32 + (lane >> 4) * 8;
    bf16x8 pk;
#pragma unroll
    for (int e = 0; e < 8; ++e)
      pk[e] = (short)f2bf(W2[(k0 + e) * 1024 + col]);
    *(bf16x8*)(w2f + tid * 8) = pk;
  } else if (tid < 8192 + 192) {
    int t2 = tid - 8192;
    int c = t2 >> 6, k = t2 & 63;
    float s = 0.f;
    for (int e = 0; e < 64; ++e) {
      float src = (c < 2) ? W_emb[c * 64 + e] : b_emb[e];
      s += src * W1[e * 64 + k];
    }
    wc[t2] = s;  // wc0[k], wc1[k], cbe[k]
  } else if (tid < 8192 + 192 + 512) {
    int q = tid - 8384;
    int lane = q & 63;
    int fr = q >> 6;          // nt*2 + ks
    int nt = fr >> 1, ks = fr & 1;
    int col = nt * 16 + (lane & 15);
    int e0 = ks * 32 + (lane >> 4) * 8;
    bf16x8 pk;
#pragma unroll
    for (int e = 0; e < 8; ++e)
      pk[e] = (short)f2bf(W1[(64 + e0 + e) * 64 + col]);
    *(bf16x8*)(w1bf + q * 8) = pk;
  }
}

// pool: block = one group, 512 threads (8 waves), launch_bounds(512,4) ->
// 2 blocks/CU, 16 waves/CU. Phase 0: hW tile via MFMA (waves 0-3);
// Phase 1: A (tile=j) into LDS in fragment order; pass-0 B-frags issued
// before the barrier. Phase 2: register-pool j-loop (R12 form, setprio
// removed: m190 measured setprio hurts barrier-synced lockstep GEMM).
__global__ __launch_bounds__(512, 4) void pool_kernel(
    const float* __restrict__ in_xy, const float* __restrict__ h_states,
    const float* __restrict__ b1, const float* __restrict__ b2,
    const unsigned short* __restrict__ w2f, const float* __restrict__ wc,
    const unsigned short* __restrict__ w1bf, float* __restrict__ out) {
  __shared__ bf16x8 Afrag[2048];  // 32 KB, fragment-ordered A (256x64 bf16), tile=j
  __shared__ float hWs[16][72];   // hW tile (pad 72 -> 16B-aligned rows)
  __shared__ float exy[32];       // x[0:16], y[16:32]
  const int g = blockIdx.x;
  const int t = threadIdx.x;
  const int lane = t & 63;
  const int wv = t >> 6;  // 0..7

  if (t < 32) {
    int p = t & 15;
    exy[t] = in_xy[((NS - 1) * NB + g * 16 + p) * 2 + (t >> 4)];
  }

  // Phase 0: hW[j][k] = b1[k] + cbe[k] + h[g*16+j] @ W1b. Waves 0-3 -> ntile wv.
  if (wv < 4) {
    const int row = g * 16 + (lane & 15);
    const int e0 = (lane >> 4) * 8;
    const float* hp = h_states + row * 64 + e0;
    bf16x8 ha0, ha1;
#pragma unroll
    for (int e = 0; e < 8; ++e) {
      ha0[e] = (short)f2bf(hp[e]);
      ha1[e] = (short)f2bf(hp[e + 32]);
    }
    bf16x8 bf0 = *(const bf16x8*)(w1bf + ((wv * 2 + 0) * 64 + lane) * 8);
    bf16x8 bf1 = *(const bf16x8*)(w1bf + ((wv * 2 + 1) * 64 + lane) * 8);
    f32x4 z = {0.f, 0.f, 0.f, 0.f};
    f32x4 acc = __builtin_amdgcn_mfma_f32_16x16x32_bf16(ha0, bf0, z, 0, 0, 0);
    acc = __builtin_amdgcn_mfma_f32_16x16x32_bf16(ha1, bf1, acc, 0, 0, 0);
    int col = wv * 16 + (lane & 15);
    float bb = b1[col] + wc[128 + col];
#pragma unroll
    for (int r = 0; r < 4; ++r)
      hWs[(lane >> 4) * 4 + r][col] = acc[r] + bb;
  }

  // epilogue bias + per-thread k-slice constants (global, L2-hot; no LDS dep)
  float b2v[8];
#pragma unroll
  for (int u = 0; u < 8; ++u)
    b2v[u] = b2[wv * 128 + u * 16 + (lane & 15)];
  const int i = t & 15;
  const int k0 = ((t >> 6) & 1) * 32 + ((t >> 4) & 3) * 8;
  float w0[8], w1[8];
#pragma unroll
  for (int e = 0; e < 8; ++e) {
    w0[e] = wc[k0 + e];
    w1[e] = wc[64 + k0 + e];
  }
  __syncthreads();

  // Phase 1: A build. Granule G = t + 512c -> lane=G&63, ks=(G>>6)&1,
  // j = (t>>7) + 4c. A_j[i,k] = relu(rel(i,j)x*wc0 + rel(i,j)y*wc1 + hW[j][k])
  {
    float exi = exy[i], eyi = exy[16 + i];
#pragma unroll
    for (int c = 0; c < 4; ++c) {
      int j = (t >> 7) + 4 * c;
      float rx = exy[j] - exi;
      float ry = exy[16 + j] - eyi;
      const f32x4* hp2 = (const f32x4*)&hWs[j][k0];
      f32x4 h0 = hp2[0], h1 = hp2[1];
      float hv[8] = {h0[0], h0[1], h0[2], h0[3], h1[0], h1[1], h1[2], h1[3]};
      bf16x8 pk;
#pragma unroll
      for (int e = 0; e < 8; ++e) {
        float v = fmaf(rx, w0[e], fmaf(ry, w1[e], hv[e]));
        v = fmaxf(v, 0.f);
        pk[e] = (short)f2bf(v);
      }
      Afrag[t + 512 * c] = pk;
    }
  }

  // Pass-0 B-fragments issued BEFORE the barrier: global-load latency overlaps
  // the barrier + other waves' A-build tail.
  bf16x8 bfr[4][2];
#pragma unroll
  for (int u = 0; u < 4; ++u) {
    int nt = wv * 8 + u;
    bfr[u][0] = *(const bf16x8*)(w2f + ((nt * 2 + 0) * 64 + lane) * 8);
    bfr[u][1] = *(const bf16x8*)(w2f + ((nt * 2 + 1) * 64 + lane) * 8);
  }
  __syncthreads();

  // Phase 2: GEMM + register pooling, 2 passes of 4 ntiles, acc double-buffer.
  const int rowbase = (g * 16 + (lane >> 4) * 4) * 1024 + wv * 128 + (lane & 15);
  const bf16x8* ap = Afrag + lane;
  const f32x4 NEGINF = {-3.4e38f, -3.4e38f, -3.4e38f, -3.4e38f};
#pragma unroll
  for (int pass = 0; pass < 2; ++pass) {
    if (pass == 1) {
#pragma unroll
      for (int u = 0; u < 4; ++u) {
        int nt = wv * 8 + 4 + u;
        bfr[u][0] = *(const bf16x8*)(w2f + ((nt * 2 + 0) * 64 + lane) * 8);
        bfr[u][1] = *(const bf16x8*)(w2f + ((nt * 2 + 1) * 64 + lane) * 8);
      }
    }
    f32x4 pool[4], accB[4];
#pragma unroll
    for (int u = 0; u < 4; ++u) { pool[u] = NEGINF; accB[u] = NEGINF; }

    bf16x8 a0 = ap[0];
    bf16x8 a1 = ap[64];
#pragma unroll
    for (int jj = 0; jj < 16; jj += 2) {
      // even iter -> accA; pool-fmax consumes accB (iter jj-1; -inf at jj=0)
      f32x4 accA[4];
#pragma unroll
      for (int u = 0; u < 4; ++u) {
        f32x4 z = {0.f, 0.f, 0.f, 0.f};
        accA[u] = __builtin_amdgcn_mfma_f32_16x16x32_bf16(a0, bfr[u][0], z, 0, 0, 0);
      }
#pragma unroll
      for (int u = 0; u < 4; ++u)
        accA[u] = __builtin_amdgcn_mfma_f32_16x16x32_bf16(a1, bfr[u][1], accA[u], 0, 0, 0);
      bf16x8 c0 = ap[(jj + 1) * 128];
      bf16x8 c1 = ap[(jj + 1) * 128 + 64];
#pragma unroll
      for (int u = 0; u < 4; ++u)
#pragma unroll
        for (int r = 0; r < 4; ++r) pool[u][r] = fmaxf(pool[u][r], accB[u][r]);

      // odd iter -> accB; pool-fmax consumes accA
#pragma unroll
      for (int u = 0; u < 4; ++u) {
        f32x4 z = {0.f, 0.f, 0.f, 0.f};
        accB[u] = __builtin_amdgcn_mfma_f32_16x16x32_bf16(c0, bfr[u][0], z, 0, 0, 0);
      }
#pragma unroll
      for (int u = 0; u < 4; ++u)
        accB[u] = __builtin_amdgcn_mfma_f32_16x16x32_bf16(c1, bfr[u][1], accB[u], 0, 0, 0);
      int jn = (jj + 2) & 15;  // wrap harmless
      a0 = ap[jn * 128];
      a1 = ap[jn * 128 + 64];
#pragma unroll
      for (int u = 0; u < 4; ++u)
#pragma unroll
        for (int r = 0; r < 4; ++r) pool[u][r] = fmaxf(pool[u][r], accA[u][r]);
    }
    // tail: accB holds j=15
#pragma unroll
    for (int u = 0; u < 4; ++u)
#pragma unroll
      for (int r = 0; r < 4; ++r) pool[u][r] = fmaxf(pool[u][r], accB[u][r]);

#pragma unroll
    for (int u = 0; u < 4; ++u) {
      float bb = b2v[pass * 4 + u];
#pragma unroll
      for (int r = 0; r < 4; ++r)
        out[rowbase + r * 1024 + (pass * 4 + u) * 16] = fmaxf(pool[u][r] + bb, 0.f);
    }
  }
}

extern "C" void kernel_launch(void* const* d_in, const int* in_sizes, int n_in,
                              void* d_out, int out_size, void* d_ws, size_t ws_size,
                              hipStream_t stream) {
  const float* in_xy = (const float*)d_in[0];
  const float* h_states = (const float*)d_in[2];
  const float* W_emb = (const float*)d_in[4];
  const float* b_emb = (const float*)d_in[5];
  const float* W1 = (const float*)d_in[6];
  const float* b1 = (const float*)d_in[7];
  const float* W2 = (const float*)d_in[8];
  const float* b2 = (const float*)d_in[9];
  float* out = (float*)d_out;

  unsigned short* w2f = (unsigned short*)d_ws;                     // 128 KB @ 0
  float* wc = (float*)((char*)d_ws + 131072);                      // 768 B
  unsigned short* w1bf = (unsigned short*)((char*)d_ws + 132096);  // 8 KB

  prep_kernel<<<35, 256, 0, stream>>>(W2, W_emb, b_emb, W1, w2f, wc, w1bf);
  pool_kernel<<<512, 512, 0, stream>>>(in_xy, h_states, b1, b2, w2f, wc, w1bf, out);
}